// Round 1
// baseline (588.833 us; speedup 1.0000x reference)
//
#include <hip/hip_runtime.h>

#define D 64
#define K 1024
#define NPTS 65536
#define OUT_ELEMS (NPTS * D)

// ---------------------------------------------------------------------------
// Prep: transpose embeddings [D][K] (row-major, element (d,k) at d*K+k) into
// eT [K][D] so each code row is contiguous; compute enorm[k] = ||e_k||^2 in
// numpy axis-0 order (sequential over d); zero the loss output slot.
// ---------------------------------------------------------------------------
__global__ __launch_bounds__(256) void vq_prep(const float* __restrict__ emb,
                                               float* __restrict__ eT,
                                               float* __restrict__ enorm,
                                               float* __restrict__ loss_out) {
    const int idx = blockIdx.x * 256 + threadIdx.x;  // 0 .. 65535, coalesced read
    const int d = idx >> 10;                          // emb flat index = d*K + k
    const int k = idx & (K - 1);
    eT[k * D + d] = emb[idx];

    if (idx < K) {
        // enorm[k]: sequential sum over d of emb[d][k]^2 (np add.reduce axis 0)
        float s = __fmul_rn(emb[idx], emb[idx]);
        for (int dd = 1; dd < D; ++dd) {
            const float v = emb[dd * K + idx];
            s = __fadd_rn(s, __fmul_rn(v, v));
        }
        enorm[idx] = s;
    }
    if (idx == 0) *loss_out = 0.0f;
}

// ---------------------------------------------------------------------------
// Main: block = 256 threads = 4 waves. Block b owns points p = b*64 + lane.
// Every wave holds the full x-row of its lane's point in VGPRs; wave w scans
// codes [w*256, (w+1)*256). LDS combine keeps the global first-index argmin.
// Epilogue: wave w writes float4 chunks [4w, 4w+4) of each point's output row
// and accumulates the loss partial; one atomicAdd per block.
// ---------------------------------------------------------------------------
__global__ __launch_bounds__(256, 4) void vq_main(const float* __restrict__ x,
                                                  const float* __restrict__ eT,
                                                  const float* __restrict__ enorm,
                                                  float* __restrict__ out,
                                                  float* __restrict__ loss_out) {
    __shared__ float sdist[4][64];
    __shared__ int   sidx[4][64];
    __shared__ float swsum[4];

    const int lane = threadIdx.x & 63;
    const int w    = threadIdx.x >> 6;
    const int p    = blockIdx.x * 64 + lane;

    // Load this point's x row (16 float4 = 64 floats) into registers.
    float4 xv[16];
    const float4* xr = (const float4*)(x + (size_t)p * D);
#pragma unroll
    for (int j = 0; j < 16; ++j) xv[j] = xr[j];

    // A = ||x||^2, replicating numpy pairwise_sum (8 accumulators, unroll-8,
    // tree combine), with explicit non-contracted fp32 ops.
    float A;
    {
        const float* xs = (const float*)xv;
        float r[8];
#pragma unroll
        for (int i = 0; i < 8; ++i) r[i] = __fmul_rn(xs[i], xs[i]);
#pragma unroll
        for (int b = 8; b < 64; b += 8) {
#pragma unroll
            for (int i = 0; i < 8; ++i)
                r[i] = __fadd_rn(r[i], __fmul_rn(xs[b + i], xs[b + i]));
        }
        A = __fadd_rn(__fadd_rn(__fadd_rn(r[0], r[1]), __fadd_rn(r[2], r[3])),
                      __fadd_rn(__fadd_rn(r[4], r[5]), __fadd_rn(r[6], r[7])));
    }

    // Scan this wave's K-chunk.
    float best = 3.402823466e38f;
    int   bi   = 0;
    const int k0 = w * 256;
    for (int kk = 0; kk < 256; ++kk) {
        const int k = k0 + kk;
        const float4* er = (const float4*)(eT + k * D);  // wave-uniform address
        float ax = 0.f, ay = 0.f, az = 0.f, aw = 0.f;
#pragma unroll
        for (int j = 0; j < 16; ++j) {
            const float4 ev = er[j];
            ax = fmaf(xv[j].x, ev.x, ax);
            ay = fmaf(xv[j].y, ev.y, ay);
            az = fmaf(xv[j].z, ev.z, az);
            aw = fmaf(xv[j].w, ev.w, aw);
        }
        const float dot  = __fadd_rn(__fadd_rn(ax, ay), __fadd_rn(az, aw));
        // Match reference rounding: (A + enorm) first, then subtract 2*dot.
        const float dist = __fsub_rn(__fadd_rn(A, enorm[k]), __fmul_rn(2.0f, dot));
        if (dist < best) { best = dist; bi = k; }   // strict <: first-index ties
    }

    sdist[w][lane] = best;
    sidx[w][lane]  = bi;
    __syncthreads();

    // Combine the 4 waves' candidates; ascending w = ascending k ranges, so
    // strict < preserves the global first-index tie-break.
    float fb = sdist[0][lane];
    int   fi = sidx[0][lane];
#pragma unroll
    for (int ww = 1; ww < 4; ++ww) {
        const float dv = sdist[ww][lane];
        const int   iv = sidx[ww][lane];
        if (dv < fb) { fb = dv; fi = iv; }
    }

    // Epilogue: gather winner row chunks, write output, loss partial.
    const float4* qr  = (const float4*)(eT + (size_t)fi * D);
    float4* orow      = (float4*)(out + (size_t)p * D);
    float lsum = 0.f;
    const int j0 = 4 * w;
#pragma unroll
    for (int jj = 0; jj < 4; ++jj) {
        const int j = j0 + jj;
        const float4 qv = qr[j];
        orow[j] = qv;
        const float dx = qv.x - xv[j].x;
        const float dy = qv.y - xv[j].y;
        const float dz = qv.z - xv[j].z;
        const float dw = qv.w - xv[j].w;
        lsum = fmaf(dx, dx, fmaf(dy, dy, fmaf(dz, dz, fmaf(dw, dw, lsum))));
    }

    // Wave reduce, then block reduce, one atomic per block.
#pragma unroll
    for (int off = 32; off > 0; off >>= 1) lsum += __shfl_down(lsum, off, 64);
    if (lane == 0) swsum[w] = lsum;
    __syncthreads();
    if (threadIdx.x == 0) {
        const float t = ((swsum[0] + swsum[1]) + (swsum[2] + swsum[3]));
        // loss = BETA*commit + codebook = 1.25 * mean((q-x)^2)
        atomicAdd(loss_out, t * (1.25f / (float)OUT_ELEMS));
    }
}

extern "C" void kernel_launch(void* const* d_in, const int* in_sizes, int n_in,
                              void* d_out, int out_size, void* d_ws, size_t ws_size,
                              hipStream_t stream) {
    const float* x   = (const float*)d_in[0];   // 64*32*32*64 fp32
    const float* emb = (const float*)d_in[1];   // 64*1024 fp32, [D][K]
    float* out       = (float*)d_out;           // [quantized (4194304) | loss (1)]
    float* eT        = (float*)d_ws;            // K*D fp32 = 256 KiB
    float* enorm     = eT + (size_t)K * D;      // K fp32
    float* loss_out  = out + OUT_ELEMS;

    vq_prep<<<dim3(K * D / 256), dim3(256), 0, stream>>>(emb, eT, enorm, loss_out);
    vq_main<<<dim3(NPTS / 64), dim3(256), 0, stream>>>(x, eT, enorm, out, loss_out);
}

// Round 2
// 559.666 us; speedup vs baseline: 1.0521x; 1.0521x over previous
//
#include <hip/hip_runtime.h>

#define D 64
#define K 1024
#define NPTS 65536
#define OUT_ELEMS (NPTS * D)
#define PAD4 17  // LDS row stride in float4 units (68 floats) — breaks bank conflicts

// ---------------------------------------------------------------------------
// Prep: transpose embeddings [D][K] into eT [K][D]; enorm[k] = ||e_k||^2 in
// numpy axis-0 order; zero the loss output slot.
// ---------------------------------------------------------------------------
__global__ __launch_bounds__(256) void vq_prep(const float* __restrict__ emb,
                                               float* __restrict__ eT,
                                               float* __restrict__ enorm,
                                               float* __restrict__ loss_out) {
    const int idx = blockIdx.x * 256 + threadIdx.x;  // 0 .. 65535
    const int d = idx >> 10;
    const int k = idx & (K - 1);
    eT[k * D + d] = emb[idx];

    if (idx < K) {
        float s = __fmul_rn(emb[idx], emb[idx]);
        for (int dd = 1; dd < D; ++dd) {
            const float v = emb[dd * K + idx];
            s = __fadd_rn(s, __fmul_rn(v, v));
        }
        enorm[idx] = s;
    }
    if (idx == 0) *loss_out = 0.0f;
}

// numpy pairwise_sum partial: sequential adds of 8 squared terms
__device__ __forceinline__ float sq8(float a, float b, float c, float d,
                                     float e, float f, float g, float h) {
    float r = __fmul_rn(a, a);
    r = __fadd_rn(r, __fmul_rn(b, b));
    r = __fadd_rn(r, __fmul_rn(c, c));
    r = __fadd_rn(r, __fmul_rn(d, d));
    r = __fadd_rn(r, __fmul_rn(e, e));
    r = __fadd_rn(r, __fmul_rn(f, f));
    r = __fadd_rn(r, __fmul_rn(g, g));
    r = __fadd_rn(r, __fmul_rn(h, h));
    return r;
}

// ---------------------------------------------------------------------------
// Main: block = 256 thr = 4 waves, owns 64 points (p = blk*64 + lane).
// x row lives in 16 NAMED float4 registers (no array -> no scratch spill).
// Wave w scans codes [w*256,(w+1)*256) (split-K); LDS combine; winner rows
// gathered into LDS and written out coalesced; wave 0 computes the loss.
// ---------------------------------------------------------------------------
__global__ __launch_bounds__(256, 2) void vq_main(const float* __restrict__ x,
                                                  const float* __restrict__ eT,
                                                  const float* __restrict__ enorm,
                                                  float* __restrict__ out,
                                                  float* __restrict__ loss_out) {
    __shared__ float4 sbuf[64 * PAD4];   // x slab, later reused for q slab
    __shared__ float  sdist[4][64];
    __shared__ int    sidx[4][64];

    const int t    = threadIdx.x;
    const int lane = t & 63;
    const int w    = t >> 6;

    // Phase 1: coalesced global read of the block's x slab (16 KiB) into LDS.
    const float4* xg = (const float4*)x + (size_t)blockIdx.x * 1024;
#pragma unroll
    for (int s = 0; s < 4; ++s) {
        const int f = s * 256 + t;           // float4 index within slab
        sbuf[(f >> 4) * PAD4 + (f & 15)] = xg[f];
    }
    __syncthreads();

    // Phase 2: lane pulls its own row into named registers.
    const float4* row = &sbuf[lane * PAD4];
    const float4 x0 = row[0],  x1 = row[1],  x2 = row[2],  x3 = row[3];
    const float4 x4 = row[4],  x5 = row[5],  x6 = row[6],  x7 = row[7];
    const float4 x8 = row[8],  x9 = row[9],  x10 = row[10], x11 = row[11];
    const float4 x12 = row[12], x13 = row[13], x14 = row[14], x15 = row[15];

    // A = ||x||^2 replicating numpy pairwise_sum (8 accs, unroll-8, tree).
    const float r0 = sq8(x0.x, x2.x, x4.x, x6.x, x8.x, x10.x, x12.x, x14.x);
    const float r1 = sq8(x0.y, x2.y, x4.y, x6.y, x8.y, x10.y, x12.y, x14.y);
    const float r2 = sq8(x0.z, x2.z, x4.z, x6.z, x8.z, x10.z, x12.z, x14.z);
    const float r3 = sq8(x0.w, x2.w, x4.w, x6.w, x8.w, x10.w, x12.w, x14.w);
    const float r4 = sq8(x1.x, x3.x, x5.x, x7.x, x9.x, x11.x, x13.x, x15.x);
    const float r5 = sq8(x1.y, x3.y, x5.y, x7.y, x9.y, x11.y, x13.y, x15.y);
    const float r6 = sq8(x1.z, x3.z, x5.z, x7.z, x9.z, x11.z, x13.z, x15.z);
    const float r7 = sq8(x1.w, x3.w, x5.w, x7.w, x9.w, x11.w, x13.w, x15.w);
    const float A = __fadd_rn(__fadd_rn(__fadd_rn(r0, r1), __fadd_rn(r2, r3)),
                              __fadd_rn(__fadd_rn(r4, r5), __fadd_rn(r6, r7)));

    // Phase 3: scan this wave's K-chunk. e-row loads are wave-uniform-address
    // float4 loads (L1/L2-resident 256 KiB codebook).
    float best = 3.402823466e38f;
    int   bi   = 0;
    const int k0 = w * 256;
    for (int kk = 0; kk < 256; ++kk) {
        const int k = k0 + kk;
        const float4* er = (const float4*)(eT + (size_t)k * D);
        const float enk = enorm[k];
        float ax = 0.f, ay = 0.f, az = 0.f, aw = 0.f;
#define FSTEP(J) { const float4 ev = er[J];               \
        ax = fmaf(x##J.x, ev.x, ax);                      \
        ay = fmaf(x##J.y, ev.y, ay);                      \
        az = fmaf(x##J.z, ev.z, az);                      \
        aw = fmaf(x##J.w, ev.w, aw); }
        FSTEP(0) FSTEP(1) FSTEP(2) FSTEP(3)
        FSTEP(4) FSTEP(5) FSTEP(6) FSTEP(7)
        FSTEP(8) FSTEP(9) FSTEP(10) FSTEP(11)
        FSTEP(12) FSTEP(13) FSTEP(14) FSTEP(15)
#undef FSTEP
        const float dot  = __fadd_rn(__fadd_rn(ax, ay), __fadd_rn(az, aw));
        const float dist = __fsub_rn(__fadd_rn(A, enk), __fmul_rn(2.0f, dot));
        if (dist < best) { best = dist; bi = k; }   // strict <: first-index ties
    }

    sdist[w][lane] = best;
    sidx[w][lane]  = bi;
    __syncthreads();

    // Phase 4+5: 4 threads per point combine the 4 wave candidates (ascending
    // w = ascending k, strict < keeps first index), then gather the winner's
    // row chunk into the LDS slab (overwrites x slab — all x reads are done).
    {
        const int p = t >> 2;
        const int c = t & 3;
        float fb = sdist[0][p];
        int   fi = sidx[0][p];
#pragma unroll
        for (int ww = 1; ww < 4; ++ww) {
            const float dv = sdist[ww][p];
            const int   iv = sidx[ww][p];
            if (dv < fb) { fb = dv; fi = iv; }
        }
        const float4* qr = (const float4*)(eT + (size_t)fi * D) + c * 4;
        float4* dst = &sbuf[p * PAD4 + c * 4];
#pragma unroll
        for (int jj = 0; jj < 4; ++jj) dst[jj] = qr[jj];
    }
    __syncthreads();

    // Phase 6: coalesced write of the block's output slab (16 KiB).
    float4* og = (float4*)out + (size_t)blockIdx.x * 1024;
#pragma unroll
    for (int s = 0; s < 4; ++s) {
        const int f = s * 256 + t;
        og[f] = sbuf[(f >> 4) * PAD4 + (f & 15)];
    }

    // Loss: wave 0 only (compile-time x indices; other waves' regs identical).
    if (w == 0) {
        const float4* qrow = &sbuf[lane * PAD4];
        float ls = 0.f;
#define LSTEP(J) { const float4 q = qrow[J];              \
        const float dx = q.x - x##J.x;                    \
        const float dy = q.y - x##J.y;                    \
        const float dz = q.z - x##J.z;                    \
        const float dw = q.w - x##J.w;                    \
        ls = fmaf(dx, dx, ls); ls = fmaf(dy, dy, ls);     \
        ls = fmaf(dz, dz, ls); ls = fmaf(dw, dw, ls); }
        LSTEP(0) LSTEP(1) LSTEP(2) LSTEP(3)
        LSTEP(4) LSTEP(5) LSTEP(6) LSTEP(7)
        LSTEP(8) LSTEP(9) LSTEP(10) LSTEP(11)
        LSTEP(12) LSTEP(13) LSTEP(14) LSTEP(15)
#undef LSTEP
#pragma unroll
        for (int off = 32; off > 0; off >>= 1) ls += __shfl_down(ls, off, 64);
        if (lane == 0)
            atomicAdd(loss_out, ls * (1.25f / (float)OUT_ELEMS));
    }
}

extern "C" void kernel_launch(void* const* d_in, const int* in_sizes, int n_in,
                              void* d_out, int out_size, void* d_ws, size_t ws_size,
                              hipStream_t stream) {
    const float* x   = (const float*)d_in[0];   // [64,32,32,64] fp32
    const float* emb = (const float*)d_in[1];   // [64,1024] fp32
    float* out       = (float*)d_out;           // [quantized | loss]
    float* eT        = (float*)d_ws;            // K*D fp32
    float* enorm     = eT + (size_t)K * D;      // K fp32
    float* loss_out  = out + OUT_ELEMS;

    vq_prep<<<dim3(K * D / 256), dim3(256), 0, stream>>>(emb, eT, enorm, loss_out);
    vq_main<<<dim3(NPTS / 64), dim3(256), 0, stream>>>(x, eT, enorm, out, loss_out);
}